// Round 4
// baseline (9926.189 us; speedup 1.0000x reference)
//
#include <hip/hip_runtime.h>

#define N_ 2048
#define T_ 512
#define B_ 32
#define NWG 64            // 64 blocks, 1 per CU -> always co-resident (256 CUs)
#define NS 32
#define DT_ 1e-4f
#define U_CONST_ 0.3f
#define TAU_F_ 1.5f
#define TAU_D_ 0.3f
#define ALPHA_ 1.5f
#define I_B_ 8.0f
#define J_EI_ 1.1f
#define J_IE_ 2.2f
#define INV_TAU 125.0f          // 1/0.008
#define INV_ALPHA (1.0f/1.5f)
#define LO_SCALE 4096.0f        // 2^12: keeps lo parts out of fp16 denormal range
#define INV_LO_SCALE 2.44140625e-4f

// d_out float offsets: all_h, all_u, all_x, all_hI, outputs
#define U_OFF  (512ull*32*2048)
#define X_OFF  (2ull*512*32*2048)
#define HI_OFF (3ull*512*32*2048)
#define OUT_OFF (HI_OFF + 512ull*32)

typedef _Float16 half8 __attribute__((ext_vector_type(8)));
typedef float f32x4 __attribute__((ext_vector_type(4)));
typedef float f32x2 __attribute__((ext_vector_type(2)));
typedef unsigned long long u64;
typedef u64 u64x2 __attribute__((ext_vector_type(2)));

// r7 critical-path model: vmcnt retires IN ORDER, so any nontemporal output
// store outstanding when the poll loop (or the arrive drain) issues its
// s_waitcnt vmcnt(0) adds HBM store-retirement latency to the publish->detect
// chain TWICE per step. Fix: the publish->poll window contains ZERO vm ops.
// All output stores are issued post-poll (overlapped with MFMA); the all_h
// store is deferred one iteration so nothing HBM-bound is outstanding at the
// arrive drain. Exchange model unchanged from r6: v streamed per step
// (step-unique addresses -> plain cached consumer loads are safe), producer
// v stores write-through sc0/sc1, per-wave wait on 16 producer flags.
__device__ u64   g_vh[T_][(B_*N_)/4];   // v hi-halves, [t][b][n] packed 4/qword (64MB)
__device__ u64   g_vl[T_][(B_*N_)/4];   // v lo-halves (pre-scaled by 2^12)     (64MB)
__device__ float g_rp[2][B_*NWG];       // R partial sums, [b][wg] (bypass-only)
__device__ unsigned g_flags[NWG*16];    // per-WG epoch flag, 64B apart

#define SYS_LD_F32(p)   __hip_atomic_load((p), __ATOMIC_RELAXED, __HIP_MEMORY_SCOPE_SYSTEM)
#define SYS_LD_U32(p)   __hip_atomic_load((p), __ATOMIC_RELAXED, __HIP_MEMORY_SCOPE_SYSTEM)
#define SYS_ST_U32(p,v) __hip_atomic_store((p), (v), __ATOMIC_RELAXED, __HIP_MEMORY_SCOPE_SYSTEM)
#define SYS_ST_F32(p,v) __hip_atomic_store((p), (v), __ATOMIC_RELAXED, __HIP_MEMORY_SCOPE_SYSTEM)

__device__ inline float rate_f(float h) {
  float z = h * INV_ALPHA;
  return ALPHA_ * (fmaxf(z, 0.0f) + log1pf(expf(-fabsf(z))));
}

// flags are monotonic within a launch; must start at 0 each launch
__global__ void init_kernel() {
  g_flags[threadIdx.x] = 0u;      // 1024 threads == NWG*16 entries
}

__global__ __launch_bounds__(256, 1) void stp_kernel(
    const float* __restrict__ inp, const float* __restrict__ W_in,
    const float* __restrict__ J, float* __restrict__ out)
{
  const int tid  = threadIdx.x;
  const int wg   = blockIdx.x;
  const int wave = tid >> 6;
  const int lane = tid & 63;

  __shared__ float sh_C[4][1024];
  __shared__ float sh_part[256];         // [gc(8)][b(32)]; gc = wave*2 + half
  __shared__ float sh_hI[32], sh_RI[32];
  __shared__ float sh_inp[2][32];        // double-buffered: written pre-barrier

  // ---- J slice -> registers as split fp16 B-fragments ----
  half8 jh[2][16], jl[2][16];
  {
    const int r = lane & 15, q = lane >> 4;
    #pragma unroll
    for (int nt = 0; nt < 2; ++nt)
      #pragma unroll
      for (int c = 0; c < 16; ++c) {
        const float* src = J + (size_t)(wg*NS + nt*16 + r) * N_ + wave*512 + c*32 + q*8;
        half8 hv, lv;
        #pragma unroll
        for (int j = 0; j < 8; ++j) {
          float f = src[j];
          _Float16 hi = (_Float16)f;
          _Float16 lo = (_Float16)((f - (float)hi) * LO_SCALE);
          hv[j] = hi; lv[j] = lo;
        }
        jh[nt][c] = hv; jl[nt][c] = lv;
      }
  }

  // thread -> (2 adjacent neurons) x (2 batches); state lives in registers
  const int np = tid & 15;               // neuron-pair index within WG
  const int n0 = wg*NS + 2*np;           // global neuron (even)
  const int bq = tid >> 4;               // batch 0..15 (+16 for c=1)
  const float w0 = W_in[n0], w1 = W_in[n0+1];

  float hh[2][2], uu[2][2], xx[2][2];
  #pragma unroll
  for (int c = 0; c < 2; ++c)
    #pragma unroll
    for (int j = 0; j < 2; ++j) { hh[c][j] = 0.0f; uu[c][j] = U_CONST_; xx[c][j] = 1.0f; }

  if (tid < 32) sh_hI[tid] = 0.0f;
  __syncthreads();

  for (int t = 0; t < T_; ++t) {
    const int pb = t & 1;
    unsigned* vhd = (unsigned*)g_vh[t];
    unsigned* vld = (unsigned*)g_vl[t];

    // ---- phase A: R, v (split fp16, write-through stores), u/x update, R-partials ----
    #pragma unroll
    for (int c = 0; c < 2; ++c) {
      const int b = bq + 16*c;
      float R0 = rate_f(hh[c][0]), R1 = rate_f(hh[c][1]);
      float v0 = uu[c][0]*xx[c][0]*R0, v1 = uu[c][1]*xx[c][1]*R1;
      _Float16 h0 = (_Float16)v0, h1 = (_Float16)v1;
      _Float16 l0 = (_Float16)((v0 - (float)h0) * LO_SCALE);
      _Float16 l1 = (_Float16)((v1 - (float)h1) * LO_SCALE);
      unsigned hp = (unsigned)__builtin_bit_cast(unsigned short, h0)
                  | ((unsigned)__builtin_bit_cast(unsigned short, h1) << 16);
      unsigned lp = (unsigned)__builtin_bit_cast(unsigned short, l0)
                  | ((unsigned)__builtin_bit_cast(unsigned short, l1) << 16);
      const unsigned idx = (unsigned)(b*N_ + n0) >> 1;
      SYS_ST_U32(vhd + idx, hp);
      SYS_ST_U32(vld + idx, lp);
      uu[c][0] += ((U_CONST_-uu[c][0])*(1.0f/TAU_F_) + U_CONST_*(1.0f-uu[c][0])*R0)*DT_;
      uu[c][1] += ((U_CONST_-uu[c][1])*(1.0f/TAU_F_) + U_CONST_*(1.0f-uu[c][1])*R1)*DT_;
      xx[c][0] += ((1.0f-xx[c][0])*(1.0f/TAU_D_) - v0)*DT_;
      xx[c][1] += ((1.0f-xx[c][1])*(1.0f/TAU_D_) - v1)*DT_;
      // WG-complete R sum for batch b lives in this 16-lane group
      float s = R0 + R1;
      s += __shfl_xor(s, 1); s += __shfl_xor(s, 2);
      s += __shfl_xor(s, 4); s += __shfl_xor(s, 8);
      if ((lane & 15) == 0) SYS_ST_F32(&g_rp[pb][b*NWG + wg], s);
    }

    // inp for THIS step, loaded before the drain (double-buffered LDS slot,
    // so lagging waves still reading sh_inp[(t-1)&1] in D are unaffected)
    if (tid < 32) sh_inp[pb][tid] = inp[t*B_ + tid];

    // ---- arrive: drain write-through stores (+inp load), publish epoch ----
    __syncthreads();                     // per-wave vmcnt(0): stores at the MALL
    if (tid == 0) SYS_ST_U32(&g_flags[wg*16], (unsigned)(t + 1));

    // ---- per-wave wait: only this wave's 16 producers; window has ZERO
    //      outstanding vm ops, so each poll iteration waits only its own load
    {
      const unsigned target = (unsigned)(t + 1);
      const int p = wave*16 + (lane & 15);
      while (true) {
        unsigned f = SYS_LD_U32(&g_flags[p*16]);
        if (__ballot(f >= target) == ~0ull) break;
        __builtin_amdgcn_s_sleep(1);
      }
    }
    __atomic_signal_fence(__ATOMIC_ACQUIRE);

    // ---- post-poll: output stores (retire overlapped with MFMA phase) ----
    #pragma unroll
    for (int c = 0; c < 2; ++c) {
      const int b = bq + 16*c;
      const size_t o = (size_t)t*(B_*N_) + (size_t)b*N_ + n0;
      f32x2 uv = {uu[c][0], uu[c][1]};
      f32x2 xv = {xx[c][0], xx[c][1]};
      __builtin_nontemporal_store(uv, (f32x2*)&out[U_OFF + o]);
      __builtin_nontemporal_store(xv, (f32x2*)&out[X_OFF + o]);
      if (t > 0) {                       // deferred all_h[t-1] (hh == h_t)
        const size_t oh = (size_t)(t-1)*(B_*N_) + (size_t)b*N_ + n0;
        f32x2 hv = {hh[c][0], hh[c][1]};
        __builtin_nontemporal_store(hv, (f32x2*)&out[oh]);
      }
    }

    // ---- per-wave R-partial gather (bypass loads; lines straddle groups) ----
    {
      const int b2 = lane & 31, half = lane >> 5;
      float s = 0.0f;
      #pragma unroll
      for (int k = 0; k < 8; ++k)
        s += SYS_LD_F32(&g_rp[pb][b2*NWG + wave*16 + half*8 + k]);
      sh_part[(wave*2 + half)*32 + b2] = s;
    }

    // ---- phase C: split-fp16 MFMA; v via plain cached dwordx4 loads ----
    {
      const int r = lane & 15, q = lane >> 4;
      const u64* vhp = g_vh[t];
      const u64* vlp = g_vl[t];
      f32x4 aH00 = {0,0,0,0}, aH01 = {0,0,0,0}, aH10 = {0,0,0,0}, aH11 = {0,0,0,0};
      f32x4 aL00 = {0,0,0,0}, aL01 = {0,0,0,0}, aL10 = {0,0,0,0}, aL11 = {0,0,0,0};
      const int base0 = (r*N_      + wave*512 + q*8) >> 2;   // qword index
      const int base1 = ((r+16)*N_ + wave*512 + q*8) >> 2;
      #pragma unroll
      for (int c = 0; c < 16; ++c) {
        const int o0 = base0 + c*8, o1 = base1 + c*8;
        u64x2 th0 = *(const u64x2*)(vhp + o0);
        u64x2 tl0 = *(const u64x2*)(vlp + o0);
        u64x2 th1 = *(const u64x2*)(vhp + o1);
        u64x2 tl1 = *(const u64x2*)(vlp + o1);
        half8 ah0 = __builtin_bit_cast(half8, th0);
        half8 al0 = __builtin_bit_cast(half8, tl0);
        half8 ah1 = __builtin_bit_cast(half8, th1);
        half8 al1 = __builtin_bit_cast(half8, tl1);
        aH00 = __builtin_amdgcn_mfma_f32_16x16x32_f16(ah0, jh[0][c], aH00, 0, 0, 0);
        aH01 = __builtin_amdgcn_mfma_f32_16x16x32_f16(ah0, jh[1][c], aH01, 0, 0, 0);
        aH10 = __builtin_amdgcn_mfma_f32_16x16x32_f16(ah1, jh[0][c], aH10, 0, 0, 0);
        aH11 = __builtin_amdgcn_mfma_f32_16x16x32_f16(ah1, jh[1][c], aH11, 0, 0, 0);
        aL00 = __builtin_amdgcn_mfma_f32_16x16x32_f16(ah0, jl[0][c], aL00, 0, 0, 0);
        aL00 = __builtin_amdgcn_mfma_f32_16x16x32_f16(al0, jh[0][c], aL00, 0, 0, 0);
        aL01 = __builtin_amdgcn_mfma_f32_16x16x32_f16(ah0, jl[1][c], aL01, 0, 0, 0);
        aL01 = __builtin_amdgcn_mfma_f32_16x16x32_f16(al0, jh[1][c], aL01, 0, 0, 0);
        aL10 = __builtin_amdgcn_mfma_f32_16x16x32_f16(ah1, jl[0][c], aL10, 0, 0, 0);
        aL10 = __builtin_amdgcn_mfma_f32_16x16x32_f16(al1, jh[0][c], aL10, 0, 0, 0);
        aL11 = __builtin_amdgcn_mfma_f32_16x16x32_f16(ah1, jl[1][c], aL11, 0, 0, 0);
        aL11 = __builtin_amdgcn_mfma_f32_16x16x32_f16(al1, jh[1][c], aL11, 0, 0, 0);
      }
      #pragma unroll
      for (int i = 0; i < 4; ++i) {
        int row = q*4 + i;                   // C/D: col=lane&15, row=quad*4+reg
        sh_C[wave][ row     *32      + r] = aH00[i] + INV_LO_SCALE*aL00[i];
        sh_C[wave][ row     *32 + 16 + r] = aH01[i] + INV_LO_SCALE*aL01[i];
        sh_C[wave][(row+16) *32      + r] = aH10[i] + INV_LO_SCALE*aL10[i];
        sh_C[wave][(row+16) *32 + 16 + r] = aH11[i] + INV_LO_SCALE*aL11[i];
      }
    }
    __syncthreads();

    // ---- h_I update (needs sh_part complete; all 4 waves contributed) ----
    if (tid < 32) {
      float s = 0.0f;
      #pragma unroll
      for (int gc = 0; gc < 8; ++gc) s += sh_part[gc*32 + tid];
      float hI = sh_hI[tid];
      sh_RI[tid] = rate_f(hI);               // pre-update R_I
      float hI2 = hI + DT_*INV_TAU*(-hI + J_IE_*s);
      sh_hI[tid] = hI2;
      if (wg == 0) out[HI_OFF + (size_t)t*B_ + tid] = hI2;  // plain cached store
    }
    __syncthreads();

    // ---- phase D: h update (registers only; all_h store is deferred) ----
    #pragma unroll
    for (int c = 0; c < 2; ++c) {
      const int b = bq + 16*c;
      const int e = b*32 + 2*np;
      float sy0 = sh_C[0][e]   + sh_C[1][e]   + sh_C[2][e]   + sh_C[3][e];
      float sy1 = sh_C[0][e+1] + sh_C[1][e+1] + sh_C[2][e+1] + sh_C[3][e+1];
      float ib = sh_inp[pb][b];
      float ri = J_EI_*INV_TAU*sh_RI[b];
      float dh0 = (-hh[c][0] + sy0 + I_B_ + ib*w0)*INV_TAU - ri;
      float dh1 = (-hh[c][1] + sy1 + I_B_ + ib*w1)*INV_TAU - ri;
      hh[c][0] += dh0*DT_;
      hh[c][1] += dh1*DT_;
    }
    // next A reads only this thread's registers; shared buffers are re-written
    // only after the next barriers -> no extra __syncthreads needed here
  }

  // final deferred all_h[T-1] store (hh == h_T)
  #pragma unroll
  for (int c = 0; c < 2; ++c) {
    const int b = bq + 16*c;
    const size_t oh = (size_t)(T_-1)*(B_*N_) + (size_t)b*N_ + n0;
    f32x2 hv = {hh[c][0], hh[c][1]};
    __builtin_nontemporal_store(hv, (f32x2*)&out[oh]);
  }
}

// outputs[t,b] = sum_n rate(all_h[t,b,n]) * W_out[n] — post-hoc, no atomics
__global__ __launch_bounds__(256) void out_kernel(
    const float* __restrict__ allh, const float* __restrict__ W_out,
    float* __restrict__ outp)
{
  const int bid = blockIdx.x;              // t*32 + b
  const int tid = threadIdx.x;
  __shared__ float red[4];
  const float* hrow = allh + (size_t)bid * N_;
  float s = 0.0f;
  #pragma unroll
  for (int i = 0; i < 8; ++i) {
    int n = tid + 256*i;
    s += rate_f(hrow[n]) * W_out[n];
  }
  s += __shfl_xor(s, 32); s += __shfl_xor(s, 16); s += __shfl_xor(s, 8);
  s += __shfl_xor(s, 4);  s += __shfl_xor(s, 2);  s += __shfl_xor(s, 1);
  if ((tid & 63) == 0) red[tid >> 6] = s;
  __syncthreads();
  if (tid == 0) outp[bid] = red[0] + red[1] + red[2] + red[3];
}

extern "C" void kernel_launch(void* const* d_in, const int* in_sizes, int n_in,
                              void* d_out, int out_size, void* d_ws, size_t ws_size,
                              hipStream_t stream)
{
  const float* inp   = (const float*)d_in[0];
  const float* W_in  = (const float*)d_in[1];
  const float* J     = (const float*)d_in[2];
  const float* W_out = (const float*)d_in[3];
  float* out = (float*)d_out;

  hipLaunchKernelGGL(init_kernel, dim3(1), dim3(NWG*16), 0, stream);
  hipLaunchKernelGGL(stp_kernel, dim3(NWG), dim3(256), 0, stream,
                     inp, W_in, J, out);
  hipLaunchKernelGGL(out_kernel, dim3(T_*B_), dim3(256), 0, stream,
                     out, W_out, out + OUT_OFF);
}

// Round 5
// 8630.270 us; speedup vs baseline: 1.1502x; 1.1502x over previous
//
#include <hip/hip_runtime.h>

#define N_ 2048
#define T_ 512
#define B_ 32
#define DT_ 1e-4f
#define U_CONST_ 0.3f
#define TAU_F_ 1.5f
#define TAU_D_ 0.3f
#define ALPHA_ 1.5f
#define I_B_ 8.0f
#define J_EI_ 1.1f
#define J_IE_ 2.2f
#define INV_TAU 125.0f          // 1/0.008
#define INV_ALPHA (1.0f/1.5f)
#define LO_SCALE 4096.0f        // 2^12: keeps lo parts out of fp16 denormal range
#define INV_LO_SCALE 2.44140625e-4f

// d_out float offsets: all_h, all_u, all_x, all_hI, outputs
#define U_OFF  (512ull*32*2048)
#define X_OFF  (2ull*512*32*2048)
#define HI_OFF (3ull*512*32*2048)
#define OUT_OFF (HI_OFF + 512ull*32)

typedef _Float16 half8 __attribute__((ext_vector_type(8)));
typedef float f32x4 __attribute__((ext_vector_type(4)));
typedef unsigned long long u64;
typedef u64 u64x2 __attribute__((ext_vector_type(2)));
typedef unsigned u32;

// r8 model: ONE KERNEL PER TIMESTEP (512 graph nodes). The HW dispatch
// pipeline provides the inter-step barrier (end-of-kernel release,
// start-of-kernel acquire) -- replaces the software MALL barrier whose
// ~15-20us/step cost proved insensitive to 4 rounds of micro-changes.
// J lives as split-fp16 in device globals (16MB total; 2MB unique per XCD
// per step -> L2-resident across steps). State h/u/x/hI lives IN the output
// arrays (all_h[t-1] IS h_t). Kernel t reads v_t (ping-pong buffer, written
// by kernel t-1), computes syn+updates, writes v_{t+1} and R-partials.
// No flags, no system-scope atomics, plain cached loads/stores everywhere.
__device__ _Float16 Jh[(size_t)N_*N_];   // 8 MB, row n, col k
__device__ _Float16 Jl[(size_t)N_*N_];   // 8 MB
__device__ u64   g_vh[2][(B_*N_)/4];     // v hi-halves, [b][n] packed 4/qword
__device__ u64   g_vl[2][(B_*N_)/4];     // v lo-halves (pre-scaled by 2^12)
__device__ float g_rp[2][B_*64];         // R row-sum partials, [b][nt]

__device__ inline float rate_f(float h) {
  float z = h * INV_ALPHA;
  return ALPHA_ * (fmaxf(z, 0.0f) + log1pf(expf(-fabsf(z))));
}

// One-time: J -> split fp16 planes; v_0 and R-partials_0 into slot 0.
__global__ __launch_bounds__(256) void prep_kernel(const float* __restrict__ J)
{
  const int idx = blockIdx.x*256 + threadIdx.x;     // 65536 threads
  for (size_t i = idx; i < (size_t)N_*N_; i += 65536) {
    float f = J[i];
    _Float16 hi = (_Float16)f;
    Jh[i] = hi;
    Jl[i] = (_Float16)((f - (float)hi) * LO_SCALE);
  }
  const float R0 = rate_f(0.0f);                    // h0 = 0
  const float v0 = U_CONST_ * 1.0f * R0;            // u0*x0*R0
  _Float16 h0 = (_Float16)v0;
  _Float16 l0 = (_Float16)((v0 - (float)h0) * LO_SCALE);
  u32 hp = (u32)__builtin_bit_cast(unsigned short, h0); hp |= hp << 16;
  u32 lp = (u32)__builtin_bit_cast(unsigned short, l0); lp |= lp << 16;
  if (idx < (B_*N_)/2) {
    ((u32*)g_vh[0])[idx] = hp;
    ((u32*)g_vl[0])[idx] = lp;
  }
  if (idx < B_*64) g_rp[0][idx] = 32.0f * R0;       // exact: 5 doublings of 2*R0
}

// grid 128 = 64 nt (32-neuron tiles) x 2 bt (16-batch halves).
// blockIdx = bt*64 + nt: stride 64 == 0 mod 8 XCDs -> bt-twins of an nt
// share an XCD -> J slice fetched into that L2 once, reused 2x and across steps.
__global__ __launch_bounds__(256) void step_kernel(
    const float* __restrict__ inp, const float* __restrict__ W_in,
    float* __restrict__ out, int t)
{
  const int tid  = threadIdx.x;
  const int nt   = blockIdx.x & 63;
  const int bt   = blockIdx.x >> 6;
  const int wave = tid >> 6;
  const int lane = tid & 63;
  const int ns = nt*32, bs = bt*16;
  const int sl = t & 1;

  __shared__ float sh_C[4][512];        // [wave][b(16) x n(32)]

  // scalar-phase identity: thread (m, np) owns batch bs+m, neurons ns+2np..+1
  const int m  = tid >> 4;
  const int np = tid & 15;
  const int b  = bs + m;
  const int n0 = ns + 2*np;

  const bool first = (t == 0);
  const size_t prev = (size_t)(t-1)*(B_*N_) + (size_t)b*N_ + n0;

  // ---- early loads: previous state tiles (h_t = all_h[t-1], etc.) ----
  float2 hv, uv, xv;
  float hI;
  if (first) {
    hv = make_float2(0.0f, 0.0f);
    uv = make_float2(U_CONST_, U_CONST_);
    xv = make_float2(1.0f, 1.0f);
    hI = 0.0f;
  } else {
    hv = *(const float2*)&out[prev];
    uv = *(const float2*)&out[U_OFF + prev];
    xv = *(const float2*)&out[X_OFF + prev];
    hI = out[HI_OFF + (size_t)(t-1)*B_ + b];
  }
  const float ib = inp[t*B_ + b];
  const float w0 = W_in[n0], w1 = W_in[n0+1];

  // ---- MFMA: syn tile [16 batches x 32 neurons], k split 512/wave ----
  {
    const int r = lane & 15, q = lane >> 4;
    const u64* vhp = g_vh[sl];
    const u64* vlp = g_vl[sl];
    const int abase = ((bs + r)*N_ + wave*512 + q*8) >> 2;   // u64 index
    const _Float16* jh0p = &Jh[(size_t)(ns + r)*N_      + wave*512 + q*8];
    const _Float16* jh1p = &Jh[(size_t)(ns + 16 + r)*N_ + wave*512 + q*8];
    const _Float16* jl0p = &Jl[(size_t)(ns + r)*N_      + wave*512 + q*8];
    const _Float16* jl1p = &Jl[(size_t)(ns + 16 + r)*N_ + wave*512 + q*8];
    f32x4 aH0 = {0,0,0,0}, aH1 = {0,0,0,0};
    f32x4 aL0 = {0,0,0,0}, aL1 = {0,0,0,0};
    #pragma unroll
    for (int c = 0; c < 16; ++c) {
      const int o = abase + c*8;                    // c*32 halves
      u64x2 th = *(const u64x2*)(vhp + o);
      u64x2 tl = *(const u64x2*)(vlp + o);
      half8 ah = __builtin_bit_cast(half8, th);
      half8 al = __builtin_bit_cast(half8, tl);
      half8 j0 = *(const half8*)(jh0p + c*32);
      half8 j1 = *(const half8*)(jh1p + c*32);
      half8 k0 = *(const half8*)(jl0p + c*32);
      half8 k1 = *(const half8*)(jl1p + c*32);
      aH0 = __builtin_amdgcn_mfma_f32_16x16x32_f16(ah, j0, aH0, 0, 0, 0);
      aH1 = __builtin_amdgcn_mfma_f32_16x16x32_f16(ah, j1, aH1, 0, 0, 0);
      aL0 = __builtin_amdgcn_mfma_f32_16x16x32_f16(ah, k0, aL0, 0, 0, 0);
      aL0 = __builtin_amdgcn_mfma_f32_16x16x32_f16(al, j0, aL0, 0, 0, 0);
      aL1 = __builtin_amdgcn_mfma_f32_16x16x32_f16(ah, k1, aL1, 0, 0, 0);
      aL1 = __builtin_amdgcn_mfma_f32_16x16x32_f16(al, j1, aL1, 0, 0, 0);
    }
    #pragma unroll
    for (int i = 0; i < 4; ++i) {
      int row = q*4 + i;                 // C/D: col=lane&15, row=quad*4+reg
      sh_C[wave][row*32      + r] = aH0[i] + INV_LO_SCALE*aL0[i];
      sh_C[wave][row*32 + 16 + r] = aH1[i] + INV_LO_SCALE*aL1[i];
    }
  }

  // ---- hI_{t+1}: nt==0 WGs own it (S_t from kernel t-1's partials) ----
  if (nt == 0 && tid < 16) {
    const int bb = bs + tid;
    float S = 0.0f;
    #pragma unroll
    for (int k2 = 0; k2 < 64; ++k2) S += g_rp[sl][bb*64 + k2];
    float hIt = first ? 0.0f : out[HI_OFF + (size_t)(t-1)*B_ + bb];
    out[HI_OFF + (size_t)t*B_ + bb] = hIt + DT_*INV_TAU*(-hIt + J_IE_*S);
  }
  __syncthreads();

  // ---- reduce syn across waves; elementwise updates; produce step t+1 ----
  const int e = m*32 + 2*np;
  float sy0 = sh_C[0][e]   + sh_C[1][e]   + sh_C[2][e]   + sh_C[3][e];
  float sy1 = sh_C[0][e+1] + sh_C[1][e+1] + sh_C[2][e+1] + sh_C[3][e+1];

  float R0 = rate_f(hv.x), R1 = rate_f(hv.y);
  float v0 = uv.x*xv.x*R0, v1 = uv.y*xv.y*R1;
  float u20 = uv.x + ((U_CONST_-uv.x)*(1.0f/TAU_F_) + U_CONST_*(1.0f-uv.x)*R0)*DT_;
  float u21 = uv.y + ((U_CONST_-uv.y)*(1.0f/TAU_F_) + U_CONST_*(1.0f-uv.y)*R1)*DT_;
  float x20 = xv.x + ((1.0f-xv.x)*(1.0f/TAU_D_) - v0)*DT_;
  float x21 = xv.y + ((1.0f-xv.y)*(1.0f/TAU_D_) - v1)*DT_;
  float ri  = J_EI_*INV_TAU*rate_f(hI);
  float h20 = hv.x + ((-hv.x + sy0 + I_B_ + ib*w0)*INV_TAU - ri)*DT_;
  float h21 = hv.y + ((-hv.y + sy1 + I_B_ + ib*w1)*INV_TAU - ri)*DT_;

  const size_t cur = (size_t)t*(B_*N_) + (size_t)b*N_ + n0;
  *(float2*)&out[cur]         = make_float2(h20, h21);
  *(float2*)&out[U_OFF + cur] = make_float2(u20, u21);
  *(float2*)&out[X_OFF + cur] = make_float2(x20, x21);

  // v_{t+1} (split fp16) into the other ping-pong slot
  float R20 = rate_f(h20), R21 = rate_f(h21);
  float nv0 = u20*x20*R20, nv1 = u21*x21*R21;
  _Float16 p0 = (_Float16)nv0, p1 = (_Float16)nv1;
  _Float16 q0 = (_Float16)((nv0 - (float)p0) * LO_SCALE);
  _Float16 q1 = (_Float16)((nv1 - (float)p1) * LO_SCALE);
  u32 hp = (u32)__builtin_bit_cast(unsigned short, p0)
         | ((u32)__builtin_bit_cast(unsigned short, p1) << 16);
  u32 lp = (u32)__builtin_bit_cast(unsigned short, q0)
         | ((u32)__builtin_bit_cast(unsigned short, q1) << 16);
  const unsigned vidx = (unsigned)(b*N_ + n0) >> 1;
  ((u32*)g_vh[sl^1])[vidx] = hp;
  ((u32*)g_vl[sl^1])[vidx] = lp;

  // R_{t+1} partial over this WG's 32 neurons (16-lane group reduce)
  float s = R20 + R21;
  s += __shfl_xor(s, 1); s += __shfl_xor(s, 2);
  s += __shfl_xor(s, 4); s += __shfl_xor(s, 8);
  if (np == 0) g_rp[sl^1][b*64 + nt] = s;
}

// outputs[t,b] = sum_n rate(all_h[t,b,n]) * W_out[n] — post-hoc
__global__ __launch_bounds__(256) void out_kernel(
    const float* __restrict__ allh, const float* __restrict__ W_out,
    float* __restrict__ outp)
{
  const int bid = blockIdx.x;              // t*32 + b
  const int tid = threadIdx.x;
  __shared__ float red[4];
  const float* hrow = allh + (size_t)bid * N_;
  float s = 0.0f;
  #pragma unroll
  for (int i = 0; i < 8; ++i) {
    int n = tid + 256*i;
    s += rate_f(hrow[n]) * W_out[n];
  }
  s += __shfl_xor(s, 32); s += __shfl_xor(s, 16); s += __shfl_xor(s, 8);
  s += __shfl_xor(s, 4);  s += __shfl_xor(s, 2);  s += __shfl_xor(s, 1);
  if ((tid & 63) == 0) red[tid >> 6] = s;
  __syncthreads();
  if (tid == 0) outp[bid] = red[0] + red[1] + red[2] + red[3];
}

extern "C" void kernel_launch(void* const* d_in, const int* in_sizes, int n_in,
                              void* d_out, int out_size, void* d_ws, size_t ws_size,
                              hipStream_t stream)
{
  const float* inp   = (const float*)d_in[0];
  const float* W_in  = (const float*)d_in[1];
  const float* J     = (const float*)d_in[2];
  const float* W_out = (const float*)d_in[3];
  float* out = (float*)d_out;

  hipLaunchKernelGGL(prep_kernel, dim3(256), dim3(256), 0, stream, J);
  for (int t = 0; t < T_; ++t)
    hipLaunchKernelGGL(step_kernel, dim3(128), dim3(256), 0, stream,
                       inp, W_in, out, t);
  hipLaunchKernelGGL(out_kernel, dim3(T_*B_), dim3(256), 0, stream,
                     out, W_out, out + OUT_OFF);
}